// Round 1
// baseline (536.336 us; speedup 1.0000x reference)
//
#include <hip/hip_runtime.h>
#include <stdint.h>

#define Bb 4
#define Tt 1024
#define Cc 768
#define Hh 12
#define Dd 64

typedef __attribute__((ext_vector_type(8))) short short8;
typedef __attribute__((ext_vector_type(4))) float f32x4;

__device__ inline unsigned short f2bf(float f) {
  union { float f; uint32_t u; } c; c.f = f;
  return (unsigned short)((c.u + 0x7FFFu + ((c.u >> 16) & 1u)) >> 16);
}

// ---------- fp32 -> bf16, same layout (x) ----------
__global__ void k_convert(const float* __restrict__ in, unsigned short* __restrict__ out, int n4) {
  int i = blockIdx.x * blockDim.x + threadIdx.x;
  if (i >= n4) return;
  float4 v = ((const float4*)in)[i];
  ushort4 o;
  o.x = f2bf(v.x); o.y = f2bf(v.y); o.z = f2bf(v.z); o.w = f2bf(v.w);
  ((ushort4*)out)[i] = o;
}

// ---------- W[K][N] fp32 -> WT[N][K] bf16 ----------
__global__ void k_transpose(const float* __restrict__ W, unsigned short* __restrict__ WT,
                            int K, int N) {
  int i = blockIdx.x * blockDim.x + threadIdx.x;
  if (i >= N * K) return;
  int n = i / K, k = i - n * K;
  WT[i] = f2bf(W[k * N + n]);
}

// ---------- GEMM: C[M][N] = A[M][K] * BT[N][K]^T + bias ----------
// mode 0: scatter epilogue -> Qb/Kb [B,H,T,D], Vt [B,H,D,T] (all bf16)
// mode 1: fp32 epilogue -> Y [M][N]
#define BM 128
#define BN 128
#define BK 32
#define LDK 40

__global__ __launch_bounds__(256, 3) void k_gemm(
    const unsigned short* __restrict__ A, const unsigned short* __restrict__ B,
    const float* __restrict__ bias, int M, int N, int K, int mode,
    unsigned short* __restrict__ Qb, unsigned short* __restrict__ Kb,
    unsigned short* __restrict__ Vt, float* __restrict__ Y)
{
  __shared__ __align__(16) unsigned short Al[BM][LDK];
  __shared__ __align__(16) unsigned short Bl[BN][LDK];
  const int nb = N / BN;
  const int m0 = (blockIdx.x / nb) * BM;
  const int n0 = (blockIdx.x % nb) * BN;
  const int tid = threadIdx.x;
  const int lane = tid & 63;
  const int w = tid >> 6;
  const int wm = (w & 1) * 64;
  const int wn = (w >> 1) * 64;
  const int l16 = lane & 15, q = lane >> 4;

  f32x4 acc[4][4];
#pragma unroll
  for (int i = 0; i < 4; ++i)
#pragma unroll
    for (int j = 0; j < 4; ++j)
#pragma unroll
      for (int e = 0; e < 4; ++e) acc[i][j][e] = 0.f;

  const int rrow = tid >> 1;       // 0..127
  const int kch = (tid & 1) * 16;  // 0 or 16 (bf16 units)

  for (int k0 = 0; k0 < K; k0 += BK) {
    int4 va0 = *(const int4*)(A + (size_t)(m0 + rrow) * K + k0 + kch);
    int4 va1 = *(const int4*)(A + (size_t)(m0 + rrow) * K + k0 + kch + 8);
    int4 vb0 = *(const int4*)(B + (size_t)(n0 + rrow) * K + k0 + kch);
    int4 vb1 = *(const int4*)(B + (size_t)(n0 + rrow) * K + k0 + kch + 8);
    __syncthreads();
    *(int4*)(&Al[rrow][kch])     = va0;
    *(int4*)(&Al[rrow][kch + 8]) = va1;
    *(int4*)(&Bl[rrow][kch])     = vb0;
    *(int4*)(&Bl[rrow][kch + 8]) = vb1;
    __syncthreads();
    short8 af[4], bfr[4];
#pragma unroll
    for (int t = 0; t < 4; ++t) {
      af[t]  = *(const short8*)(&Al[wm + t * 16 + l16][q * 8]);
      bfr[t] = *(const short8*)(&Bl[wn + t * 16 + l16][q * 8]);
    }
#pragma unroll
    for (int i = 0; i < 4; ++i)
#pragma unroll
      for (int j = 0; j < 4; ++j)
        acc[i][j] = __builtin_amdgcn_mfma_f32_16x16x32_bf16(af[i], bfr[j], acc[i][j], 0, 0, 0);
  }

#pragma unroll
  for (int i = 0; i < 4; ++i)
#pragma unroll
    for (int j = 0; j < 4; ++j) {
      int mg = m0 + wm + i * 16 + q * 4;
      int ng = n0 + wn + j * 16 + l16;
      float bv = bias[ng];
#pragma unroll
      for (int r = 0; r < 4; ++r) {
        float v = acc[i][j][r] + bv;
        int mr = mg + r;
        if (mode == 0) {
          int which = ng / Cc;
          int nn = ng - which * Cc;
          int hh = nn >> 6, d = nn & 63;
          int bb = mr >> 10, t = mr & 1023;
          int bh = bb * Hh + hh;
          unsigned short o = f2bf(v);
          if (which == 0)      Qb[((size_t)bh * Tt + t) * Dd + d] = o;
          else if (which == 1) Kb[((size_t)bh * Tt + t) * Dd + d] = o;
          else                 Vt[((size_t)bh * Dd + d) * Tt + t] = o;
        } else {
          Y[(size_t)mr * N + ng] = v;
        }
      }
    }
}

// ---------- attention: 1 block = (b,h, 32 rows) x full 1024 cols ----------
// Swapped QK^T orientation: S = mfma(K_frag, Q_frag) so that the C-fragment
// has lane(l16) = query row t, (q*4+r) = 4 CONSECUTIVE key cols s.
// => bias/mask loads and attn stores are float4; P staging is ushort4.
__global__ __launch_bounds__(256, 2) void k_attn(
    const unsigned short* __restrict__ Qb, const unsigned short* __restrict__ Kb,
    const unsigned short* __restrict__ Vt,
    const float* __restrict__ bias, const float* __restrict__ mask,
    float* __restrict__ attn, unsigned short* __restrict__ Ob)
{
  __shared__ __align__(16) unsigned short Pl[4][32][136];
  __shared__ float red[4][32];
  __shared__ float rowmax[32];
  __shared__ float rowinv[32];

  const int bid = blockIdx.x;
  const int bh = bid >> 5;
  const int tile = bid & 31;
  const int b = bh / Hh;
  const int h = bh - b * Hh;
  const int row0 = tile * 32;
  const int tid = threadIdx.x, lane = tid & 63, w = tid >> 6;
  const int l16 = lane & 15, q = lane >> 4;
  const int colw = w * 256;

  const unsigned short* Qp = Qb + ((size_t)bh * Tt + row0) * Dd;
  const unsigned short* Kp = Kb + (size_t)bh * Tt * Dd;
  const unsigned short* Vp = Vt + (size_t)bh * Dd * Tt;
  const float* bp = bias + ((size_t)bh * Tt + row0) * Tt;
  const float* mp = mask + ((size_t)b * Tt + row0) * Tt;
  float* ap = attn + ((size_t)bh * Tt + row0) * Tt;

  // Q fragments: lane l16 = row t within 16-block, elements = k chunk.
  short8 qf[2][2];
#pragma unroll
  for (int mt = 0; mt < 2; ++mt)
#pragma unroll
    for (int ks = 0; ks < 2; ++ks)
      qf[mt][ks] = *(const short8*)(Qp + (mt * 16 + l16) * Dd + ks * 32 + q * 8);

  f32x4 S[2][16];
#pragma unroll
  for (int mt = 0; mt < 2; ++mt)
#pragma unroll
    for (int nt = 0; nt < 16; ++nt)
#pragma unroll
      for (int e = 0; e < 4; ++e) S[mt][nt][e] = 0.f;

  // S^T = K Q^T over this wave's 256 columns: mfma(kf, qf)
  __builtin_amdgcn_s_setprio(1);
#pragma unroll
  for (int nt = 0; nt < 16; ++nt) {
    int col = colw + nt * 16 + l16;
#pragma unroll
    for (int ks = 0; ks < 2; ++ks) {
      short8 kf = *(const short8*)(Kp + (size_t)col * Dd + ks * 32 + q * 8);
      S[0][nt] = __builtin_amdgcn_mfma_f32_16x16x32_bf16(kf, qf[0][ks], S[0][nt], 0, 0, 0);
      S[1][nt] = __builtin_amdgcn_mfma_f32_16x16x32_bf16(kf, qf[1][ks], S[1][nt], 0, 0, 0);
    }
  }
  __builtin_amdgcn_s_setprio(0);

  // logits = S*scale + bias + mask  (float4 per (mt,nt))
#pragma unroll
  for (int mt = 0; mt < 2; ++mt) {
    const float* bR = bp + (size_t)(mt * 16 + l16) * Tt + colw + q * 4;
    const float* mR = mp + (size_t)(mt * 16 + l16) * Tt + colw + q * 4;
#pragma unroll
    for (int nt = 0; nt < 16; ++nt) {
      f32x4 bv = *(const f32x4*)(bR + nt * 16);
      f32x4 mv = *(const f32x4*)(mR + nt * 16);
      S[mt][nt] = S[mt][nt] * 0.125f + bv + mv;
    }
  }

  // row max: row t = l16 is lane-local; reduce across the 4 q-groups then waves
#pragma unroll
  for (int mt = 0; mt < 2; ++mt) {
    float m = S[mt][0][0];
#pragma unroll
    for (int nt = 0; nt < 16; ++nt)
#pragma unroll
      for (int r = 0; r < 4; ++r) m = fmaxf(m, S[mt][nt][r]);
    m = fmaxf(m, __shfl_xor(m, 16, 64));
    m = fmaxf(m, __shfl_xor(m, 32, 64));
    if (q == 0) red[w][mt * 16 + l16] = m;
  }
  __syncthreads();
  if (tid < 32)
    rowmax[tid] = fmaxf(fmaxf(red[0][tid], red[1][tid]), fmaxf(red[2][tid], red[3][tid]));
  __syncthreads();

  // exp + row sum
#pragma unroll
  for (int mt = 0; mt < 2; ++mt) {
    float m = rowmax[mt * 16 + l16];
    float s = 0.f;
#pragma unroll
    for (int nt = 0; nt < 16; ++nt)
#pragma unroll
      for (int r = 0; r < 4; ++r) {
        float p = __expf(S[mt][nt][r] - m);
        S[mt][nt][r] = p;
        s += p;
      }
    s += __shfl_xor(s, 16, 64);
    s += __shfl_xor(s, 32, 64);
    if (q == 0) red[w][mt * 16 + l16] = s;
  }
  __syncthreads();
  if (tid < 32)
    rowinv[tid] = 1.0f / (red[0][tid] + red[1][tid] + red[2][tid] + red[3][tid]);
  __syncthreads();

  // normalize, write attn (float4), stage P (ushort4) per 128-col half, then P·V
  f32x4 O[2][4];
#pragma unroll
  for (int mt = 0; mt < 2; ++mt)
#pragma unroll
    for (int dt = 0; dt < 4; ++dt)
#pragma unroll
      for (int e = 0; e < 4; ++e) O[mt][dt][e] = 0.f;

  for (int half = 0; half < 2; ++half) {
    __syncthreads();
#pragma unroll
    for (int mt = 0; mt < 2; ++mt) {
      float inv = rowinv[mt * 16 + l16];
      float* apR = ap + (size_t)(mt * 16 + l16) * Tt + colw + q * 4;
#pragma unroll
      for (int nn = 0; nn < 8; ++nn) {
        int nt = half * 8 + nn;
        f32x4 p = S[mt][nt] * inv;
        *(f32x4*)(apR + nt * 16) = p;
        ushort4 pb;
        pb.x = f2bf(p[0]); pb.y = f2bf(p[1]); pb.z = f2bf(p[2]); pb.w = f2bf(p[3]);
        *(ushort4*)(&Pl[w][mt * 16 + l16][nn * 16 + q * 4]) = pb;
      }
    }
    __syncthreads();
    __builtin_amdgcn_s_setprio(1);
#pragma unroll
    for (int kt = 0; kt < 4; ++kt) {
      short8 pf0 = *(const short8*)(&Pl[w][l16][kt * 32 + q * 8]);
      short8 pf1 = *(const short8*)(&Pl[w][16 + l16][kt * 32 + q * 8]);
#pragma unroll
      for (int dt = 0; dt < 4; ++dt) {
        short8 vf = *(const short8*)(Vp + (size_t)(dt * 16 + l16) * Tt
                                     + colw + half * 128 + kt * 32 + q * 8);
        O[0][dt] = __builtin_amdgcn_mfma_f32_16x16x32_bf16(pf0, vf, O[0][dt], 0, 0, 0);
        O[1][dt] = __builtin_amdgcn_mfma_f32_16x16x32_bf16(pf1, vf, O[1][dt], 0, 0, 0);
      }
    }
    __builtin_amdgcn_s_setprio(0);
  }

  // cross-wave O reduction through LDS (reuse Pl)
  __syncthreads();
  float* Op = (float*)&Pl[0][0][0] + w * 2048;
#pragma unroll
  for (int mt = 0; mt < 2; ++mt)
#pragma unroll
    for (int dt = 0; dt < 4; ++dt)
#pragma unroll
      for (int r = 0; r < 4; ++r) {
        int row = mt * 16 + q * 4 + r;
        int d = dt * 16 + l16;
        Op[row * 64 + d] = O[mt][dt][r];
      }
  __syncthreads();
  float* base = (float*)&Pl[0][0][0];
  for (int e = tid; e < 2048; e += 256) {
    float v = base[e] + base[2048 + e] + base[4096 + e] + base[6144 + e];
    int row = e >> 6, d = e & 63;
    Ob[((size_t)(b * Tt + row0 + row)) * Cc + h * Dd + d] = f2bf(v);
  }
}

extern "C" void kernel_launch(void* const* d_in, const int* in_sizes, int n_in,
                              void* d_out, int out_size, void* d_ws, size_t ws_size,
                              hipStream_t stream) {
  const float* x     = (const float*)d_in[0];
  const float* maskl = (const float*)d_in[1];
  const float* bias  = (const float*)d_in[2];
  const float* Wqkv  = (const float*)d_in[3];
  const float* bqkv  = (const float*)d_in[4];
  const float* Wproj = (const float*)d_in[5];
  const float* bproj = (const float*)d_in[6];
  float* y    = (float*)d_out;
  float* attn = y + (size_t)Bb * Tt * Cc;

  char* ws = (char*)d_ws;
  unsigned short* xb     = (unsigned short*)(ws);             // 6,291,456 B
  unsigned short* WqkvT  = (unsigned short*)(ws + 6291456);   // 3,538,944 B
  unsigned short* WprojT = (unsigned short*)(ws + 9830400);   // 1,179,648 B
  unsigned short* Qb     = (unsigned short*)(ws + 11010048);  // 6,291,456 B
  unsigned short* Kb     = (unsigned short*)(ws + 17301504);  // 6,291,456 B
  unsigned short* Vt     = (unsigned short*)(ws + 23592960);  // 6,291,456 B
  unsigned short* Ob     = (unsigned short*)(ws + 29884416);  // 6,291,456 B -> 36,175,872 total

  k_convert<<<3072, 256, 0, stream>>>(x, xb, 786432);
  k_transpose<<<6912, 256, 0, stream>>>(Wqkv, WqkvT, 768, 2304);
  k_transpose<<<2304, 256, 0, stream>>>(Wproj, WprojT, 768, 768);
  k_gemm<<<576, 256, 0, stream>>>(xb, WqkvT, bqkv, 4096, 2304, 768, 0,
                                  Qb, Kb, Vt, nullptr);
  k_attn<<<1536, 256, 0, stream>>>(Qb, Kb, Vt, bias, maskl, attn, Ob);
  k_gemm<<<192, 256, 0, stream>>>(Ob, WprojT, bproj, 4096, 768, 768, 1,
                                  nullptr, nullptr, nullptr, y);
}